// Round 5
// baseline (251.824 us; speedup 1.0000x reference)
//
#include <hip/hip_runtime.h>

#define BN    64
#define KCLS  3
#define PPIX  147456
#define NB1   4096

// streaming-kernel geometry: 64 rows x 32 chunks = 2048 blocks = 8 blocks/CU
#define BPR    32
#define F4PB   (PPIX / 4 / BPR)     // 1152 float4 groups per block (4.5/thread)

// rowselect geometry (unchanged from verified r3/r4)
#define RS_THREADS 1024
#define RS_F4      (PPIX / 4 / RS_THREADS)   // 36 float4 per thread
#define CAPS       8192                      // LDS candidate cap

// ---------------- workspace layout (bytes) ----------------
static const size_t OFF_NLL  = 0;                                   // 37,748,736
static const size_t OFF_GH   = (size_t)BN * PPIX * 4;               // ghist: 1 MB (zeroed)
static const size_t OFF_ACC  = OFF_GH + (size_t)BN * NB1 * 4;       // 8 B (zeroed)
static const size_t OFF_DONE = OFF_ACC + 8;                         // 8 B (zeroed)
static const size_t ZERO_END = OFF_DONE + 8;

__device__ __forceinline__ unsigned topk_count(const int* sp_ptr) {
    double sp = (double)sp_ptr[0];
    if (sp > 1.0) sp = 1.0;
    return (unsigned)(sp * 0.15 * (double)PPIX + (1.0 - sp) * (double)PPIX);
}

__device__ __forceinline__ float sel_nll(int t, float a, float b, float c) {
    float lp = (t == 0) ? a : ((t == 1) ? b : ((t == 2) ? c : 0.0f));
    return fmaxf(-lp, 0.0f);   // nll >= 0; kill -0.0
}

// ---------------- kernel 1a: pure-stream NLL (no LDS, no atomics) -----------
// Ablation arm A: if the r4 fusion was poisoning the memory pipeline, this
// runs at streaming BW (~30-40us). Reads in+tgt, writes nll. Nothing else.
__global__ __launch_bounds__(256) void k_nll(
    const float* __restrict__ in, const int* __restrict__ tgt,
    float* __restrict__ nll)
{
    const int tid   = threadIdx.x;
    const int row   = blockIdx.x / BPR;
    const int chunk = blockIdx.x % BPR;
    const float4* p0 = (const float4*)(in + (size_t)row * KCLS * PPIX);
    const float4* p1 = p0 + PPIX / 4;
    const float4* p2 = p1 + PPIX / 4;
    const int4*   t4 = (const int4*)(tgt + (size_t)row * PPIX);
    float4*       n4 = (float4*)(nll + (size_t)row * PPIX);
    const int base = chunk * F4PB;

    #pragma unroll
    for (int j = 0; j < 4; ++j) {
        const int idx = base + j * 256 + tid;
        const int4   t = t4[idx];
        const float4 a = p0[idx];
        const float4 b = p1[idx];
        const float4 c = p2[idx];
        float4 v;
        v.x = sel_nll(t.x, a.x, b.x, c.x);
        v.y = sel_nll(t.y, a.y, b.y, c.y);
        v.z = sel_nll(t.z, a.z, b.z, c.z);
        v.w = sel_nll(t.w, a.w, b.w, c.w);
        n4[idx] = v;
    }
    if (tid < (F4PB - 4 * 256)) {      // tail: 5th group for tid < 128
        const int idx = base + 4 * 256 + tid;
        const int4   t = t4[idx];
        const float4 a = p0[idx];
        const float4 b = p1[idx];
        const float4 c = p2[idx];
        float4 v;
        v.x = sel_nll(t.x, a.x, b.x, c.x);
        v.y = sel_nll(t.y, a.y, b.y, c.y);
        v.z = sel_nll(t.z, a.z, b.z, c.z);
        v.w = sel_nll(t.w, a.w, b.w, c.w);
        n4[idx] = v;
    }
}

// ---------------- kernel 1b: histogram from nll (LDS atomics + flush) -------
// Ablation arm B: reads back the just-written nll (L2/L3-hot), builds the
// per-row 4096-bin histogram. If THIS costs >=40us, atomics are the wall.
__global__ __launch_bounds__(256) void k_hist2(
    const float* __restrict__ nll, unsigned* __restrict__ cnt1)
{
    __shared__ unsigned lc[NB1];   // 16 KB -> 8 blocks/CU
    const int tid = threadIdx.x;
    for (int i = tid; i < NB1; i += 256) lc[i] = 0u;
    __syncthreads();

    const int row   = blockIdx.x / BPR;
    const int chunk = blockIdx.x % BPR;
    const float4* n4 = (const float4*)(nll + (size_t)row * PPIX);
    const int base = chunk * F4PB;

    #pragma unroll
    for (int j = 0; j < 4; ++j) {
        const float4 v = n4[base + j * 256 + tid];
        atomicAdd(&lc[__float_as_uint(v.x) >> 19], 1u);
        atomicAdd(&lc[__float_as_uint(v.y) >> 19], 1u);
        atomicAdd(&lc[__float_as_uint(v.z) >> 19], 1u);
        atomicAdd(&lc[__float_as_uint(v.w) >> 19], 1u);
    }
    if (tid < (F4PB - 4 * 256)) {      // tail: 5th group for tid < 128
        const float4 v = n4[base + 4 * 256 + tid];
        atomicAdd(&lc[__float_as_uint(v.x) >> 19], 1u);
        atomicAdd(&lc[__float_as_uint(v.y) >> 19], 1u);
        atomicAdd(&lc[__float_as_uint(v.z) >> 19], 1u);
        atomicAdd(&lc[__float_as_uint(v.w) >> 19], 1u);
    }
    __syncthreads();

    unsigned* gc = cnt1 + (size_t)row * NB1;
    for (int i = tid; i < NB1; i += 256) {
        const unsigned cc = lc[i];
        if (cc) atomicAdd(&gc[i], cc);
    }
}

// ---------------- kernel 2: per-row scan + compact + resolve + mean ---------
// (byte-identical to verified r3/r4)
__global__ __launch_bounds__(RS_THREADS, 1) void k_rowselect(
    const float* __restrict__ nll, const unsigned* __restrict__ ghist,
    const int* __restrict__ sp, double* __restrict__ accum,
    unsigned* __restrict__ done, float* __restrict__ out)
{
    __shared__ float    stage[CAPS];     // 32 KB — candidates, persists to resolve
    __shared__ double   dd[RS_THREADS];  // 8 KB — dred, then sum-prefix scratch
    __shared__ unsigned cs[RS_THREADS];  // 4 KB — count-prefix scratch
    __shared__ unsigned lc2[1024];       // 4 KB — level-2/3 count hist
    __shared__ float    ls2[1024];       // 4 KB — level-2/3 sum hist
    __shared__ int s_b1, s_r1, s_lcnt, s_b2, s_r2;
    __shared__ double s_S0, s_S2;

    const int row = blockIdx.x;
    const int tid = threadIdx.x;

    // ---- level 1: descending scan of ghist (4 bins/thread) ----
    const unsigned* ghr = ghist + (size_t)row * NB1;
    unsigned cl[4]; unsigned cacc = 0u;
    #pragma unroll
    for (int i = 0; i < 4; ++i) {
        cl[i] = ghr[NB1 - 1 - (tid * 4 + i)];
        cacc += cl[i];
    }
    cs[tid] = cacc;
    __syncthreads();
    for (int off = 1; off < RS_THREADS; off <<= 1) {
        unsigned t2 = (tid >= off) ? cs[tid - off] : 0u;
        __syncthreads();
        cs[tid] += t2;
        __syncthreads();
    }
    const unsigned k = topk_count(sp);
    {
        unsigned cum = tid ? cs[tid - 1] : 0u;
        #pragma unroll
        for (int i = 0; i < 4; ++i) {
            const unsigned cb = cl[i];
            if (cum < k && cum + cb >= k) {      // exactly one (thread,i) hits
                s_b1 = NB1 - 1 - (tid * 4 + i);
                s_r1 = (int)(k - cum);
            }
            cum += cb;
        }
    }
    if (tid == 0) s_lcnt = 0;
    __syncthreads();

    // ---- stream this row's nll: S_above (f64) + stage bin-b1 candidates ----
    const unsigned b1 = (unsigned)s_b1;
    const unsigned lo = b1 << 19;
    const unsigned hi = (b1 + 1u) << 19;   // b1==4095 -> 0x80000000 > all v>=0
    const float4* n4 = (const float4*)(nll + (size_t)row * PPIX);

    double acc = 0.0;
    #pragma unroll
    for (int j = 0; j < RS_F4; ++j) {
        const float4 f = n4[j * RS_THREADS + tid];
        const float vv[4] = {f.x, f.y, f.z, f.w};
        #pragma unroll
        for (int q = 0; q < 4; ++q) {
            const unsigned u = __float_as_uint(vv[q]);
            if (u >= hi) {
                acc += (double)vv[q];
            } else if (u >= lo) {
                const int s = atomicAdd(&s_lcnt, 1);
                if (s < CAPS) stage[s] = vv[q];
            }
        }
    }
    dd[tid] = acc;
    __syncthreads();
    for (int s = RS_THREADS / 2; s > 0; s >>= 1) {
        if (tid < s) dd[tid] += dd[tid + s];
        __syncthreads();
    }
    if (tid == 0) s_S0 = dd[0];
    int n = s_lcnt; if (n > CAPS) n = CAPS;   // valid: covered by the sync above

    // ---- level 2: 1024-bin hist over bits[18:9] of candidates ----
    lc2[tid] = 0u; ls2[tid] = 0.0f;
    __syncthreads();
    for (int i = tid; i < n; i += RS_THREADS) {
        const float v = stage[i];
        const unsigned key = (__float_as_uint(v) >> 9) & 0x3FFu;
        atomicAdd(&lc2[key], 1u);
        atomicAdd(&ls2[key], v);
    }
    __syncthreads();

    // descending scan, 1 bin/thread
    {
        const unsigned c2 = lc2[1023 - tid];
        const float    f2 = ls2[1023 - tid];
        cs[tid] = c2; dd[tid] = (double)f2;
        __syncthreads();
        for (int off = 1; off < RS_THREADS; off <<= 1) {
            unsigned tc = 0u; double td = 0.0;
            if (tid >= off) { tc = cs[tid - off]; td = dd[tid - off]; }
            __syncthreads();
            cs[tid] += tc; dd[tid] += td;
            __syncthreads();
        }
        const unsigned k2 = (unsigned)s_r1;
        const unsigned cum = tid ? cs[tid - 1] : 0u;
        const double   sS  = tid ? dd[tid - 1] : 0.0;
        if (cum < k2 && cum + c2 >= k2) {        // exactly one thread
            s_b2 = 1023 - tid;
            s_r2 = (int)(k2 - cum);
            s_S2 = sS;
        }
    }
    __syncthreads();

    // ---- level 3: 512-bin hist over bits[8:0], filtered to b2 ----
    const unsigned b2 = (unsigned)s_b2;
    if (tid < 512) { lc2[tid] = 0u; ls2[tid] = 0.0f; }
    __syncthreads();
    for (int i = tid; i < n; i += RS_THREADS) {
        const float v = stage[i];
        const unsigned bits = __float_as_uint(v);
        if (((bits >> 9) & 0x3FFu) == b2) {
            atomicAdd(&lc2[bits & 0x1FFu], 1u);
            atomicAdd(&ls2[bits & 0x1FFu], v);
        }
    }
    __syncthreads();
    {
        const unsigned c3 = (tid < 512) ? lc2[511 - tid] : 0u;
        const float    f3 = (tid < 512) ? ls2[511 - tid] : 0.0f;
        cs[tid] = c3; dd[tid] = (double)f3;
        __syncthreads();
        for (int off = 1; off < RS_THREADS; off <<= 1) {
            unsigned tc = 0u; double td = 0.0;
            if (tid >= off) { tc = cs[tid - off]; td = dd[tid - off]; }
            __syncthreads();
            cs[tid] += tc; dd[tid] += td;
            __syncthreads();
        }
        const unsigned k3 = (unsigned)s_r2;
        const unsigned cum = tid ? cs[tid - 1] : 0u;
        const double   S3  = tid ? dd[tid - 1] : 0.0;
        if (cum < k3 && cum + c3 >= k3) {        // exactly one thread finalizes
            const int      bin3 = 511 - tid;
            const unsigned r3   = k3 - cum;
            const float tval = __uint_as_float((b1 << 19) | (b2 << 9) | (unsigned)bin3);
            const double total = s_S0 + s_S2 + S3 + (double)r3 * (double)tval;
            atomicAdd(accum, total);             // device-scope f64 atomic
            __threadfence();
            const unsigned ticket =
                __hip_atomic_fetch_add(done, 1u, __ATOMIC_ACQ_REL, __HIP_MEMORY_SCOPE_AGENT);
            if (ticket == BN - 1) {              // last row writes the mean
                const double a2 =
                    __hip_atomic_load(accum, __ATOMIC_RELAXED, __HIP_MEMORY_SCOPE_AGENT);
                out[0] = (float)(a2 / ((double)BN * (double)topk_count(sp)));
            }
        }
    }
}

// ======================= launch =============================================
extern "C" void kernel_launch(void* const* d_in, const int* in_sizes, int n_in,
                              void* d_out, int out_size, void* d_ws, size_t ws_size,
                              hipStream_t stream)
{
    (void)in_sizes; (void)n_in; (void)out_size; (void)ws_size;
    const float* in  = (const float*)d_in[0];
    const int*   tgt = (const int*)d_in[1];
    const int*   sp  = (const int*)d_in[2];

    char* ws = (char*)d_ws;
    float*    nll   = (float*)(ws + OFF_NLL);
    unsigned* ghist = (unsigned*)(ws + OFF_GH);
    double*   accum = (double*)(ws + OFF_ACC);
    unsigned* done  = (unsigned*)(ws + OFF_DONE);

    // zero: ghist + accum + done (contiguous)
    hipMemsetAsync(ws + OFF_GH, 0, ZERO_END - OFF_GH, stream);

    k_nll      <<<BN * BPR, 256,        0, stream>>>(in, tgt, nll);
    k_hist2    <<<BN * BPR, 256,        0, stream>>>(nll, ghist);
    k_rowselect<<<BN,       RS_THREADS, 0, stream>>>(nll, ghist, sp, accum, done,
                                                     (float*)d_out);
}